// Round 1
// baseline (1012.514 us; speedup 1.0000x reference)
//
#include <hip/hip_runtime.h>

// ---------------------------------------------------------------------------
// UserSpotConv: bipartite GCN aggregation.
//   spot_out[s] = sum_{e: s_e=s} user_x[u_e] / sqrt(deg_u[u_e]*deg_s[s_e])
//   user_out[u] = sum_{e: u_e=u} spot_x[s_e] / sqrt(deg_u[u_e]*deg_s[s_e])
// Strategy: counting-sort CSR build (4M int atomics) + atomic-free register
// gather (wave per row, lane owns 2 columns). Avoids 512M f32 atomics.
// ---------------------------------------------------------------------------

__global__ void deg_kernel(const int* __restrict__ u, const int* __restrict__ s,
                           int E, int* __restrict__ udeg, int* __restrict__ sdeg) {
    int i = blockIdx.x * blockDim.x + threadIdx.x;
    if (i < E) {
        atomicAdd(&udeg[u[i]], 1);
        atomicAdd(&sdeg[s[i]], 1);
    }
}

// Exclusive scan, single block of 1024 threads, 4 elems/thread per chunk.
// Writes out[0..n-1] = exclusive prefix, out[n] = total.
__global__ __launch_bounds__(1024) void scan_kernel(const int* __restrict__ in,
                                                    int* __restrict__ out, int n) {
    __shared__ int ws[17];
    const int tid  = threadIdx.x;
    const int lane = tid & 63;
    const int wid  = tid >> 6;
    int carry = 0;  // meaningful on tid 0 only
    for (int base = 0; base < n; base += 4096) {
        int idx = base + tid * 4;
        int v0 = (idx + 0 < n) ? in[idx + 0] : 0;
        int v1 = (idx + 1 < n) ? in[idx + 1] : 0;
        int v2 = (idx + 2 < n) ? in[idx + 2] : 0;
        int v3 = (idx + 3 < n) ? in[idx + 3] : 0;
        int tsum = v0 + v1 + v2 + v3;
        int x = tsum;
#pragma unroll
        for (int d = 1; d < 64; d <<= 1) {
            int t = __shfl_up(x, d);
            if (lane >= d) x += t;
        }
        if (lane == 63) ws[wid] = x;
        __syncthreads();
        if (tid == 0) {
            int run = carry;
#pragma unroll
            for (int w = 0; w < 16; ++w) { int t = ws[w]; ws[w] = run; run += t; }
            carry = run;
        }
        __syncthreads();
        int excl = ws[wid] + (x - tsum);
        if (idx + 0 < n) out[idx + 0] = excl; excl += v0;
        if (idx + 1 < n) out[idx + 1] = excl; excl += v1;
        if (idx + 2 < n) out[idx + 2] = excl; excl += v2;
        if (idx + 3 < n) out[idx + 3] = excl;
        __syncthreads();  // protect ws before next chunk's writes
    }
    if (tid == 0) out[n] = carry;
}

__global__ void init_kernel(const int* __restrict__ udeg, const int* __restrict__ sdeg,
                            const int* __restrict__ uoff, const int* __restrict__ soff,
                            int* __restrict__ ucur, int* __restrict__ scur,
                            float* __restrict__ isd_u, float* __restrict__ isd_s,
                            int n_user, int m_spot) {
    int i = blockIdx.x * blockDim.x + threadIdx.x;
    if (i < n_user) {
        ucur[i] = uoff[i];
        int d = udeg[i];
        isd_u[i] = d > 0 ? rsqrtf((float)d) : 0.f;
    }
    if (i < m_spot) {
        scur[i] = soff[i];
        int d = sdeg[i];
        isd_s[i] = d > 0 ? rsqrtf((float)d) : 0.f;
    }
}

__global__ void init_isd_kernel(const int* __restrict__ udeg, const int* __restrict__ sdeg,
                                float* __restrict__ isd_u, float* __restrict__ isd_s,
                                int n_user, int m_spot) {
    int i = blockIdx.x * blockDim.x + threadIdx.x;
    if (i < n_user) { int d = udeg[i]; isd_u[i] = d > 0 ? rsqrtf((float)d) : 0.f; }
    if (i < m_spot) { int d = sdeg[i]; isd_s[i] = d > 0 ? rsqrtf((float)d) : 0.f; }
}

__global__ void fill_kernel(const int* __restrict__ u, const int* __restrict__ s, int E,
                            int* __restrict__ ucur, int* __restrict__ scur,
                            int* __restrict__ csr_u, int* __restrict__ csr_s) {
    int i = blockIdx.x * blockDim.x + threadIdx.x;
    if (i < E) {
        int uu = u[i], ss = s[i];
        int p = atomicAdd(&ucur[uu], 1);
        csr_u[p] = ss;
        int q = atomicAdd(&scur[ss], 1);
        csr_s[q] = uu;
    }
}

// One wave per output row; lane owns columns {2*lane, 2*lane+1}.
__global__ __launch_bounds__(256) void gather_kernel(const float* __restrict__ x_src,
                                                     const int* __restrict__ nbr,
                                                     const int* __restrict__ off,
                                                     const float* __restrict__ isd_dst,
                                                     const float* __restrict__ isd_src,
                                                     float* __restrict__ out, int n_rows) {
    const int lane = threadIdx.x & 63;
    const int row  = blockIdx.x * 4 + (threadIdx.x >> 6);
    if (row >= n_rows) return;
    const int jbeg = off[row];
    const int jend = off[row + 1];
    const float wd = isd_dst[row];
    float ax = 0.f, ay = 0.f;
    if (jbeg < jend) {
        int sidx = nbr[jbeg];
        for (int j = jbeg; j < jend; ++j) {
            int snext = (j + 1 < jend) ? nbr[j + 1] : 0;   // prefetch next index
            float w = wd * isd_src[sidx];
            const float2 v = *reinterpret_cast<const float2*>(x_src + (size_t)sidx * 128 + lane * 2);
            ax = fmaf(v.x, w, ax);
            ay = fmaf(v.y, w, ay);
            sidx = snext;
        }
    }
    float2 r; r.x = ax; r.y = ay;
    *reinterpret_cast<float2*>(out + (size_t)row * 128 + lane * 2) = r;
}

// Fallback (small workspace): per-edge atomic scatter, wave per edge.
__global__ __launch_bounds__(256) void scatter_kernel(const float* __restrict__ spot_x,
                                                      const float* __restrict__ user_x,
                                                      const int* __restrict__ u,
                                                      const int* __restrict__ s, int E,
                                                      const float* __restrict__ isd_u,
                                                      const float* __restrict__ isd_s,
                                                      float* __restrict__ spot_out,
                                                      float* __restrict__ user_out) {
    const int lane = threadIdx.x & 63;
    const int e = blockIdx.x * 4 + (threadIdx.x >> 6);
    if (e >= E) return;
    const int uu = u[e], ss = s[e];
    const float w = isd_u[uu] * isd_s[ss];
    const float2 sv = *reinterpret_cast<const float2*>(spot_x + (size_t)ss * 128 + lane * 2);
    const float2 uv = *reinterpret_cast<const float2*>(user_x + (size_t)uu * 128 + lane * 2);
    atomicAdd(&user_out[(size_t)uu * 128 + lane * 2 + 0], sv.x * w);
    atomicAdd(&user_out[(size_t)uu * 128 + lane * 2 + 1], sv.y * w);
    atomicAdd(&spot_out[(size_t)ss * 128 + lane * 2 + 0], uv.x * w);
    atomicAdd(&spot_out[(size_t)ss * 128 + lane * 2 + 1], uv.y * w);
}

extern "C" void kernel_launch(void* const* d_in, const int* in_sizes, int n_in,
                              void* d_out, int out_size, void* d_ws, size_t ws_size,
                              hipStream_t stream) {
    const float* spot_x = (const float*)d_in[0];
    const float* user_x = (const float*)d_in[1];
    const int*   edges  = (const int*)d_in[2];
    const int M = in_sizes[0] / 128;   // spots
    const int N = in_sizes[1] / 128;   // users
    const int E = in_sizes[2] / 2;
    const int* u = edges;        // user_spot[0]
    const int* s = edges + E;    // user_spot[1]
    float* spot_out = (float*)d_out;
    float* user_out = (float*)d_out + (size_t)M * 128;

    // Workspace layout (fallback-critical arrays first).
    char* ws = (char*)d_ws;
    int*   udeg  = (int*)ws;   ws += sizeof(int) * N;
    int*   sdeg  = (int*)ws;   ws += sizeof(int) * M;
    float* isd_u = (float*)ws; ws += sizeof(float) * N;
    float* isd_s = (float*)ws; ws += sizeof(float) * M;
    size_t fallback_needed = (size_t)(ws - (char*)d_ws);
    int*   uoff  = (int*)ws;   ws += sizeof(int) * (N + 1);
    int*   soff  = (int*)ws;   ws += sizeof(int) * (M + 1);
    int*   ucur  = (int*)ws;   ws += sizeof(int) * N;
    int*   scur  = (int*)ws;   ws += sizeof(int) * M;
    int*   csr_u = (int*)ws;   ws += sizeof(int) * (size_t)E;  // spot idx per user-slot
    int*   csr_s = (int*)ws;   ws += sizeof(int) * (size_t)E;  // user idx per spot-slot
    size_t csr_needed = (size_t)(ws - (char*)d_ws);

    // Degree histogram (zeroed every call — ws is not re-poisoned between replays).
    hipMemsetAsync(udeg, 0, sizeof(int) * (size_t)(N + M), stream);
    deg_kernel<<<(E + 255) / 256, 256, 0, stream>>>(u, s, E, udeg, sdeg);

    const int nm = (N > M) ? N : M;
    if (csr_needed <= ws_size) {
        scan_kernel<<<1, 1024, 0, stream>>>(udeg, uoff, N);
        scan_kernel<<<1, 1024, 0, stream>>>(sdeg, soff, M);
        init_kernel<<<(nm + 255) / 256, 256, 0, stream>>>(udeg, sdeg, uoff, soff,
                                                          ucur, scur, isd_u, isd_s, N, M);
        fill_kernel<<<(E + 255) / 256, 256, 0, stream>>>(u, s, E, ucur, scur, csr_u, csr_s);
        // user_out: gather spot features over user-CSR
        gather_kernel<<<(N + 3) / 4, 256, 0, stream>>>(spot_x, csr_u, uoff,
                                                       isd_u, isd_s, user_out, N);
        // spot_out: gather user features over spot-CSR
        gather_kernel<<<(M + 3) / 4, 256, 0, stream>>>(user_x, csr_s, soff,
                                                       isd_s, isd_u, spot_out, M);
    } else if (fallback_needed <= ws_size) {
        init_isd_kernel<<<(nm + 255) / 256, 256, 0, stream>>>(udeg, sdeg, isd_u, isd_s, N, M);
        hipMemsetAsync(d_out, 0, sizeof(float) * (size_t)out_size, stream);
        scatter_kernel<<<((size_t)E + 3) / 4, 256, 0, stream>>>(spot_x, user_x, u, s, E,
                                                                isd_u, isd_s, spot_out, user_out);
    }
}

// Round 2
// 749.797 us; speedup vs baseline: 1.3504x; 1.3504x over previous
//
#include <hip/hip_runtime.h>
#include <stdint.h>

// ---------------------------------------------------------------------------
// UserSpotConv: bipartite GCN aggregation.
//   user_out[u] = sum_{e: u_e=u} spot_x[s_e] / sqrt(deg_u * deg_s)
//   spot_out[s] = sum_{e: s_e=s} user_x[u_e] / sqrt(deg_u * deg_s)
// Round 2: replace the scattered-write CSR fill (405 us, 240 MB WRITE_SIZE,
// ~16x partial-line amplification across 8 non-coherent XCD L2s) with a
// two-level counting sort:
//   part_kernel : LDS-staged partition into 128-node buckets; global writes
//                 are contiguous per-bucket runs (~150-230 B) -> ~1.4x amp.
//   bsort_kernel: per-bucket final sort; scatter region is the bucket's own
//                 ~30 KB CSR segment -> L2-local, full-line writebacks only.
// ---------------------------------------------------------------------------

#define NPB_LOG2 7
#define NPB 128            // destination nodes per bucket
#define MAXB 512           // max buckets supported by part_kernel LDS
#define PART_CHUNK 12288   // edges per block in part_kernel

__global__ void deg_kernel(const int* __restrict__ u, const int* __restrict__ s,
                           int E, int* __restrict__ udeg, int* __restrict__ sdeg) {
    int i = blockIdx.x * blockDim.x + threadIdx.x;
    if (i < E) {
        atomicAdd(&udeg[u[i]], 1);
        atomicAdd(&sdeg[s[i]], 1);
    }
}

// Exclusive scan, single block of 1024 threads, 4 elems/thread per chunk.
// Writes out[0..n-1] = exclusive prefix, out[n] = total.
__global__ __launch_bounds__(1024) void scan_kernel(const int* __restrict__ in,
                                                    int* __restrict__ out, int n) {
    __shared__ int ws[17];
    const int tid  = threadIdx.x;
    const int lane = tid & 63;
    const int wid  = tid >> 6;
    int carry = 0;  // meaningful on tid 0 only
    for (int base = 0; base < n; base += 4096) {
        int idx = base + tid * 4;
        int v0 = (idx + 0 < n) ? in[idx + 0] : 0;
        int v1 = (idx + 1 < n) ? in[idx + 1] : 0;
        int v2 = (idx + 2 < n) ? in[idx + 2] : 0;
        int v3 = (idx + 3 < n) ? in[idx + 3] : 0;
        int tsum = v0 + v1 + v2 + v3;
        int x = tsum;
#pragma unroll
        for (int d = 1; d < 64; d <<= 1) {
            int t = __shfl_up(x, d);
            if (lane >= d) x += t;
        }
        if (lane == 63) ws[wid] = x;
        __syncthreads();
        if (tid == 0) {
            int run = carry;
#pragma unroll
            for (int w = 0; w < 16; ++w) { int t = ws[w]; ws[w] = run; run += t; }
            carry = run;
        }
        __syncthreads();
        int excl = ws[wid] + (x - tsum);
        if (idx + 0 < n) out[idx + 0] = excl; excl += v0;
        if (idx + 1 < n) out[idx + 1] = excl; excl += v1;
        if (idx + 2 < n) out[idx + 2] = excl; excl += v2;
        if (idx + 3 < n) out[idx + 3] = excl;
        __syncthreads();  // protect ws before next chunk's writes
    }
    if (tid == 0) out[n] = carry;
}

__global__ void init_isd_kernel(const int* __restrict__ udeg, const int* __restrict__ sdeg,
                                float* __restrict__ isd_u, float* __restrict__ isd_s,
                                int n_user, int m_spot) {
    int i = blockIdx.x * blockDim.x + threadIdx.x;
    if (i < n_user) { int d = udeg[i]; isd_u[i] = d > 0 ? rsqrtf((float)d) : 0.f; }
    if (i < m_spot) { int d = sdeg[i]; isd_s[i] = d > 0 ? rsqrtf((float)d) : 0.f; }
}

__global__ void gcur_init_kernel(const int* __restrict__ uoff, const int* __restrict__ soff,
                                 int* __restrict__ gcur_u, int* __restrict__ gcur_s,
                                 int nbu, int nbs) {
    int i = blockIdx.x * blockDim.x + threadIdx.x;
    if (i < nbu) gcur_u[i] = uoff[i << NPB_LOG2];
    if (i < nbs) gcur_s[i] = soff[i << NPB_LOG2];
}

// Partition edges into NPB-node buckets of the primary (destination) index.
// Staged in LDS so global writes are contiguous per-bucket runs.
__global__ __launch_bounds__(256) void part_kernel(
        const int* __restrict__ prim, const int* __restrict__ sec, int E,
        int nb, int* __restrict__ gcur, uint32_t* __restrict__ out) {
    __shared__ int hist[MAXB];
    __shared__ int loff[MAXB + 1];
    __shared__ int gbase[MAXB];
    __shared__ int cur[MAXB];
    __shared__ uint32_t sbuf[PART_CHUNK];
    const int tid = threadIdx.x;
    const int beg = blockIdx.x * PART_CHUNK;
    const int end = min(beg + PART_CHUNK, E);
    for (int b = tid; b < nb; b += 256) hist[b] = 0;
    __syncthreads();
    for (int i = beg + tid; i < end; i += 256)
        atomicAdd(&hist[prim[i] >> NPB_LOG2], 1);
    __syncthreads();
    if (tid == 0) {
        int run = 0;
        for (int b = 0; b < nb; ++b) { loff[b] = run; run += hist[b]; }
        loff[nb] = run;
    }
    __syncthreads();
    for (int b = tid; b < nb; b += 256) {
        cur[b] = loff[b];
        int c = loff[b + 1] - loff[b];
        gbase[b] = c > 0 ? atomicAdd(&gcur[b], c) : 0;
    }
    __syncthreads();
    for (int i = beg + tid; i < end; i += 256) {
        int p = prim[i], s = sec[i];
        int b = p >> NPB_LOG2;
        int l = atomicAdd(&cur[b], 1);
        sbuf[l] = ((uint32_t)p << 16) | (uint32_t)s;
    }
    __syncthreads();
    const int wid = tid >> 6, lane = tid & 63;
    for (int b = wid; b < nb; b += 4) {
        int lo = loff[b], cnt = loff[b + 1] - lo, gb = gbase[b];
        for (int k = lane; k < cnt; k += 64)
            out[gb + k] = sbuf[lo + k];
    }
}

// Final counting sort within one bucket; scatter region = the bucket's own
// contiguous CSR segment (~30 KB) -> stays in the local XCD L2.
__global__ __launch_bounds__(256) void bsort_kernel(
        const uint32_t* __restrict__ packed, const int* __restrict__ noff,
        int nodes, int* __restrict__ csr) {
    __shared__ int cur[NPB];
    const int tid = threadIdx.x;
    const int ubase = blockIdx.x << NPB_LOG2;
    const int nin = min(NPB, nodes - ubase);
    if (tid < nin) cur[tid] = noff[ubase + tid];
    __syncthreads();
    const int jbeg = noff[ubase];
    const int jend = noff[ubase + nin];
    for (int j = jbeg + tid; j < jend; j += 256) {
        uint32_t p = packed[j];
        int local = (int)(p >> 16) - ubase;
        int slot = atomicAdd(&cur[local], 1);
        csr[slot] = (int)(p & 0xffffu);
    }
}

// One wave per output row; lane owns columns {2*lane, 2*lane+1}.
__global__ __launch_bounds__(256) void gather_kernel(const float* __restrict__ x_src,
                                                     const int* __restrict__ nbr,
                                                     const int* __restrict__ off,
                                                     const float* __restrict__ isd_dst,
                                                     const float* __restrict__ isd_src,
                                                     float* __restrict__ out, int n_rows) {
    const int lane = threadIdx.x & 63;
    const int row  = blockIdx.x * 4 + (threadIdx.x >> 6);
    if (row >= n_rows) return;
    const int jbeg = off[row];
    const int jend = off[row + 1];
    const float wd = isd_dst[row];
    float ax = 0.f, ay = 0.f;
    if (jbeg < jend) {
        int sidx = nbr[jbeg];
        for (int j = jbeg; j < jend; ++j) {
            int snext = (j + 1 < jend) ? nbr[j + 1] : 0;   // prefetch next index
            float w = wd * isd_src[sidx];
            const float2 v = *reinterpret_cast<const float2*>(x_src + (size_t)sidx * 128 + lane * 2);
            ax = fmaf(v.x, w, ax);
            ay = fmaf(v.y, w, ay);
            sidx = snext;
        }
    }
    float2 r; r.x = ax; r.y = ay;
    *reinterpret_cast<float2*>(out + (size_t)row * 128 + lane * 2) = r;
}

// Fallback (small workspace): per-edge atomic scatter, wave per edge.
__global__ __launch_bounds__(256) void scatter_kernel(const float* __restrict__ spot_x,
                                                      const float* __restrict__ user_x,
                                                      const int* __restrict__ u,
                                                      const int* __restrict__ s, int E,
                                                      const float* __restrict__ isd_u,
                                                      const float* __restrict__ isd_s,
                                                      float* __restrict__ spot_out,
                                                      float* __restrict__ user_out) {
    const int lane = threadIdx.x & 63;
    const int e = blockIdx.x * 4 + (threadIdx.x >> 6);
    if (e >= E) return;
    const int uu = u[e], ss = s[e];
    const float w = isd_u[uu] * isd_s[ss];
    const float2 sv = *reinterpret_cast<const float2*>(spot_x + (size_t)ss * 128 + lane * 2);
    const float2 uv = *reinterpret_cast<const float2*>(user_x + (size_t)uu * 128 + lane * 2);
    atomicAdd(&user_out[(size_t)uu * 128 + lane * 2 + 0], sv.x * w);
    atomicAdd(&user_out[(size_t)uu * 128 + lane * 2 + 1], sv.y * w);
    atomicAdd(&spot_out[(size_t)ss * 128 + lane * 2 + 0], uv.x * w);
    atomicAdd(&spot_out[(size_t)ss * 128 + lane * 2 + 1], uv.y * w);
}

extern "C" void kernel_launch(void* const* d_in, const int* in_sizes, int n_in,
                              void* d_out, int out_size, void* d_ws, size_t ws_size,
                              hipStream_t stream) {
    const float* spot_x = (const float*)d_in[0];
    const float* user_x = (const float*)d_in[1];
    const int*   edges  = (const int*)d_in[2];
    const int M = in_sizes[0] / 128;   // spots
    const int N = in_sizes[1] / 128;   // users
    const int E = in_sizes[2] / 2;
    const int* u = edges;        // user_spot[0]
    const int* s = edges + E;    // user_spot[1]
    float* spot_out = (float*)d_out;
    float* user_out = (float*)d_out + (size_t)M * 128;

    const int nbu = (N + NPB - 1) / NPB;
    const int nbs = (M + NPB - 1) / NPB;

    // Workspace layout (fallback-critical arrays first).
    char* ws = (char*)d_ws;
    int*      udeg  = (int*)ws;      ws += sizeof(int) * N;     // udeg+sdeg contiguous (memset)
    int*      sdeg  = (int*)ws;      ws += sizeof(int) * M;
    float*    isd_u = (float*)ws;    ws += sizeof(float) * N;
    float*    isd_s = (float*)ws;    ws += sizeof(float) * M;
    size_t fallback_needed = (size_t)(ws - (char*)d_ws);
    int*      uoff  = (int*)ws;      ws += sizeof(int) * (N + 1);
    int*      soff  = (int*)ws;      ws += sizeof(int) * (M + 1);
    int*      gcu   = (int*)ws;      ws += sizeof(int) * nbu;
    int*      gcs   = (int*)ws;      ws += sizeof(int) * nbs;
    uint32_t* bufA  = (uint32_t*)ws; ws += sizeof(uint32_t) * (size_t)E;  // packed edges
    int*      bufB  = (int*)ws;      ws += sizeof(int) * (size_t)E;       // CSR neighbors
    size_t csr_needed = (size_t)(ws - (char*)d_ws);

    // Degree histogram (zeroed every call — ws is not re-poisoned between replays).
    hipMemsetAsync(udeg, 0, sizeof(int) * (size_t)(N + M), stream);
    deg_kernel<<<(E + 255) / 256, 256, 0, stream>>>(u, s, E, udeg, sdeg);

    const int nm = (N > M) ? N : M;
    if (csr_needed <= ws_size && nbu <= MAXB && nbs <= MAXB) {
        scan_kernel<<<1, 1024, 0, stream>>>(udeg, uoff, N);
        scan_kernel<<<1, 1024, 0, stream>>>(sdeg, soff, M);
        init_isd_kernel<<<(nm + 255) / 256, 256, 0, stream>>>(udeg, sdeg, isd_u, isd_s, N, M);
        gcur_init_kernel<<<(nbs + 255) / 256, 256, 0, stream>>>(uoff, soff, gcu, gcs, nbu, nbs);

        const int gpart = (E + PART_CHUNK - 1) / PART_CHUNK;
        // user direction: prim=u, sec=s
        part_kernel<<<gpart, 256, 0, stream>>>(u, s, E, nbu, gcu, bufA);
        bsort_kernel<<<nbu, 256, 0, stream>>>(bufA, uoff, N, bufB);
        gather_kernel<<<(N + 3) / 4, 256, 0, stream>>>(spot_x, bufB, uoff,
                                                       isd_u, isd_s, user_out, N);
        // spot direction: prim=s, sec=u (reuses bufA/bufB — stream-ordered)
        part_kernel<<<gpart, 256, 0, stream>>>(s, u, E, nbs, gcs, bufA);
        bsort_kernel<<<nbs, 256, 0, stream>>>(bufA, soff, M, bufB);
        gather_kernel<<<(M + 3) / 4, 256, 0, stream>>>(user_x, bufB, soff,
                                                       isd_s, isd_u, spot_out, M);
    } else if (fallback_needed <= ws_size) {
        init_isd_kernel<<<(nm + 255) / 256, 256, 0, stream>>>(udeg, sdeg, isd_u, isd_s, N, M);
        hipMemsetAsync(d_out, 0, sizeof(float) * (size_t)out_size, stream);
        scatter_kernel<<<((size_t)E + 3) / 4, 256, 0, stream>>>(spot_x, user_x, u, s, E,
                                                                isd_u, isd_s, spot_out, user_out);
    }
}